// Round 3
// baseline (182.332 us; speedup 1.0000x reference)
//
#include <hip/hip_runtime.h>

#define S_LEN 2048
#define EMB_D 1024
#define QK_SCALE 0.08838834764831845f  // 1/sqrt(128)
#define LOG2E 1.4426950408889634f

typedef __bf16 bf16x8 __attribute__((ext_vector_type(8)));
typedef float f32x4 __attribute__((ext_vector_type(4)));
typedef unsigned short ushort_t;

typedef const __attribute__((address_space(1))) void gvoid;
typedef __attribute__((address_space(3))) void lvoid;

__device__ __forceinline__ unsigned short f2bf(float x) {
    unsigned u = __float_as_uint(x);
    unsigned r = u + 0x7FFFu + ((u >> 16) & 1u);  // RNE
    return (unsigned short)(r >> 16);
}

__device__ __forceinline__ void bfsplit(float x, unsigned short& hi, unsigned short& lo) {
    hi = f2bf(x);
    lo = f2bf(x - __uint_as_float((unsigned)hi << 16));
}

__device__ __forceinline__ void gl_lds(const void* g, void* l) {
    __builtin_amdgcn_global_load_lds((gvoid*)g, (lvoid*)l, 16, 0, 0);
}

// ---------------- kernel 1: transpose gate weights (3072x8 -> 16x3072)
__global__ __launch_bounds__(256) void ktrans(const float* __restrict__ igk,
                                              const float* __restrict__ fgk,
                                              float* __restrict__ wt) {
    int idx = blockIdx.x * 256 + threadIdx.x;
    if (idx < 3072 * 8) {
        int i = idx >> 3, h = idx & 7;
        wt[h * 3072 + i] = igk[idx];
        wt[(h + 8) * 3072 + i] = fgk[idx];
    }
}

// ---------------- kernel 2: gate preactivations (transposed out) + Q/K bf16 hi/lo
// pre-split, pre-scaled, pre-swizzled tile writes. 4 rows per block.
__global__ __launch_bounds__(256) void kgates(const float* __restrict__ q,
                                              const float* __restrict__ k,
                                              const float* __restrict__ v,
                                              const float* __restrict__ igb,
                                              const float* __restrict__ fgb,
                                              const float* __restrict__ wt,
                                              float* __restrict__ igp_t,
                                              float* __restrict__ fgp_t,
                                              ushort_t* __restrict__ QhG,
                                              ushort_t* __restrict__ QlG,
                                              ushort_t* __restrict__ KhG,
                                              ushort_t* __restrict__ KlG) {
    __shared__ float xs[4][3072];
    const int t = threadIdx.x;
    const int row0 = blockIdx.x * 4;
    #pragma unroll
    for (int p = 0; p < 12; ++p) {
        int c = p * 256 + t;          // float4 index 0..3071
        int r = c / 768;
        int gcol = (c % 768) * 4;
        int grow = row0 + r;
        const float* base = (gcol < 1024) ? (q + (size_t)grow * EMB_D + gcol)
                          : (gcol < 2048) ? (k + (size_t)grow * EMB_D + gcol - 1024)
                                          : (v + (size_t)grow * EMB_D + gcol - 2048);
        float4 val = *(const float4*)base;
        *(float4*)&xs[r][gcol] = val;
    }
    __syncthreads();

    // --- Q/K hi/lo bf16 tiles (swizzled layout: byte (r*256+d*2)^((r&7)<<4) within 64x128 tile)
    const int batch = row0 >> 11;
    const int sl0 = row0 & 2047;
    #pragma unroll
    for (int pp = 0; pp < 2; ++pp) {
        int chunk = pp * 256 + t;          // 0..511
        int r = chunk >> 7;                // row 0..3
        int e0 = (chunk & 127) * 8;        // emb 0..1016
        int hh = e0 >> 7, d0 = e0 & 127;
        int sl = sl0 + r;
        size_t tb = ((size_t)(batch * 8 + hh) * 32 + (sl >> 6)) * 16384;
        int off = (((sl & 63) * 256 + d0 * 2) ^ ((sl & 7) << 4));
        union { ushort_t u[8]; uint4 v4; } H, L;
        #pragma unroll
        for (int e = 0; e < 8; ++e) bfsplit(xs[r][e0 + e] * QK_SCALE, H.u[e], L.u[e]);
        *(uint4*)((char*)QhG + tb + off) = H.v4;
        *(uint4*)((char*)QlG + tb + off) = L.v4;
        #pragma unroll
        for (int e = 0; e < 8; ++e) bfsplit(xs[r][1024 + e0 + e], H.u[e], L.u[e]);
        *(uint4*)((char*)KhG + tb + off) = H.v4;
        *(uint4*)((char*)KlG + tb + off) = L.v4;
    }

    // --- gate dot products
    const int w = t >> 6, lane = t & 63;
    for (int c = 0; c < 4; ++c) {
        int o = w * 4 + c;  // 0..15
        const float* wc = wt + o * 3072;
        float a0 = 0.f, a1 = 0.f, a2 = 0.f, a3 = 0.f;
        for (int i = lane; i < 3072; i += 64) {
            float wv = wc[i];
            a0 += wv * xs[0][i]; a1 += wv * xs[1][i];
            a2 += wv * xs[2][i]; a3 += wv * xs[3][i];
        }
        #pragma unroll
        for (int m = 32; m; m >>= 1) {
            a0 += __shfl_xor(a0, m); a1 += __shfl_xor(a1, m);
            a2 += __shfl_xor(a2, m); a3 += __shfl_xor(a3, m);
        }
        if (lane == 0) {
            int h2 = o & 7;
            float bias = (o < 8) ? igb[h2] : fgb[h2];
            float* dst = (o < 8) ? igp_t : fgp_t;
            size_t bb = (size_t)(batch * 8 + h2) * S_LEN + sl0;
            dst[bb + 0] = a0 + bias; dst[bb + 1] = a1 + bias;
            dst[bb + 2] = a2 + bias; dst[bb + 3] = a3 + bias;
        }
    }
}

// ---------------- kernel 3: V transpose into swizzled bf16 tiles [bh][ct][128d][64j]
__global__ __launch_bounds__(256) void kvt(const float* __restrict__ v,
                                           ushort_t* __restrict__ VtG) {
    __shared__ float ts[64][132];
    const int blk = blockIdx.x;
    const int bh = blk >> 5, ct = blk & 31;
    const int b = bh >> 3, h = bh & 7;
    const int t = threadIdx.x;
    const float* vb = v + ((size_t)b * S_LEN + ct * 64) * EMB_D + h * 128;
    #pragma unroll
    for (int i = 0; i < 8; ++i) {
        int f = i * 256 + t;         // float4 idx 0..2047
        int r = f >> 5, c4 = f & 31;
        float4 g = *(const float4*)(vb + (size_t)r * EMB_D + c4 * 4);
        *(float4*)&ts[r][c4 * 4] = g;
    }
    __syncthreads();
    char* dst = (char*)VtG + ((size_t)bh * 32 + ct) * 16384;
    #pragma unroll
    for (int i = 0; i < 4; ++i) {
        int chunk = i * 256 + t;      // 0..1023
        int d = chunk >> 3, jl0 = (chunk & 7) * 8;
        union { ushort_t u[8]; uint4 v4; } P;
        #pragma unroll
        for (int e = 0; e < 8; ++e) P.u[e] = f2bf(ts[jl0 + e][d]);
        int swz = ((d & 7) ^ ((d >> 3) & 7)) << 4;
        *(uint4*)(dst + ((d * 128 + jl0 * 2) ^ swz)) = P.v4;
    }
}

// ---------------- kernel 4: per-(b,h) prefix scans, single wave each, no barriers.
__global__ __launch_bounds__(64) void kscan(const float* __restrict__ igp_t,
                                            const float* __restrict__ fgp_t,
                                            float* __restrict__ a_w,
                                            float* __restrict__ pm_w,
                                            float* __restrict__ cs_w) {
    const int bh = blockIdx.x;
    const int l = threadIdx.x;
    const int base = bh * S_LEN + l * 32;
    float lf[32];
    #pragma unroll
    for (int i = 0; i < 8; ++i) {
        float4 fg = *(const float4*)(fgp_t + base + i * 4);
        float* p = &lf[i * 4];
        p[0] = fminf(fg.x, 0.f) - log1pf(__expf(-fabsf(fg.x)));
        p[1] = fminf(fg.y, 0.f) - log1pf(__expf(-fabsf(fg.y)));
        p[2] = fminf(fg.z, 0.f) - log1pf(__expf(-fabsf(fg.z)));
        p[3] = fminf(fg.w, 0.f) - log1pf(__expf(-fabsf(fg.w)));
    }
    #pragma unroll
    for (int i = 1; i < 32; ++i) lf[i] += lf[i - 1];
    float tot = lf[31];
    #pragma unroll
    for (int d = 1; d < 64; d <<= 1) {
        float n = __shfl_up(tot, d, 64);
        if (l >= d) tot += n;
    }
    float excl = tot - lf[31];
    float a[32];
    #pragma unroll
    for (int i = 0; i < 8; ++i) {
        float4 ig = *(const float4*)(igp_t + base + i * 4);
        float iv[4] = {ig.x, ig.y, ig.z, ig.w};
        #pragma unroll
        for (int e = 0; e < 4; ++e) {
            int idx = i * 4 + e;
            float cs = excl + lf[idx];
            cs_w[base + idx] = cs;
            a[idx] = iv[e] - cs;
            a_w[base + idx] = a[idx];
        }
    }
    float am[32];
    am[0] = a[0];
    #pragma unroll
    for (int i = 1; i < 32; ++i) am[i] = fmaxf(am[i - 1], a[i]);
    float mtot = am[31];
    #pragma unroll
    for (int d = 1; d < 64; d <<= 1) {
        float n = __shfl_up(mtot, d, 64);
        if (l >= d) mtot = fmaxf(mtot, n);
    }
    float exm = __shfl_up(mtot, 1, 64);
    if (l == 0) exm = -INFINITY;
    #pragma unroll
    for (int i = 0; i < 32; ++i) pm_w[base + i] = fmaxf(exm, am[i]);
}

// ---------------- kernel 5: main core. 512 blocks x 256 thr (4 waves, 2x2 wave grid).
// Block = (bh, row-tile rt), longest-first. All staging via global_load_lds from
// pre-split/pre-swizzled bf16 tiles. QK^T split precision (3 MFMAs).
__global__ __launch_bounds__(256) void kmain(const ushort_t* __restrict__ QhG,
                                             const ushort_t* __restrict__ QlG,
                                             const ushort_t* __restrict__ KhG,
                                             const ushort_t* __restrict__ KlG,
                                             const ushort_t* __restrict__ VtG,
                                             const float* __restrict__ a_w,
                                             const float* __restrict__ pm_w,
                                             const float* __restrict__ cs_w,
                                             float* __restrict__ out) {
    __shared__ __align__(16) ushort_t KsH[8192];  // 16KB (Q-hi staging, then K-hi)
    __shared__ __align__(16) ushort_t KsL[8192];
    __shared__ __align__(16) ushort_t Vs[8192];
    __shared__ __align__(16) ushort_t Cs[4096];   // 8KB bf16 C tile
    __shared__ float a_sh[64];
    __shared__ float red[2][64];

    const int blk = blockIdx.x;
    const int bh = blk & 15;              // b&7 == bh&7 -> per-bh XCD affinity
    const int rt = 31 - (blk >> 4);       // longest-first dispatch
    const int row0 = rt * 64;
    const int b = bh >> 3, h = bh & 7;
    const int t = threadIdx.x;
    const int w = t >> 6, lane = t & 63;
    const int wr = w >> 1, wc = w & 1;    // 2x2 wave grid
    const int lg = lane >> 4, ll = lane & 15;

    const size_t bhoff = (size_t)bh * 524288;  // bytes per bh (2048*128*2)
    const char* qh_t = (const char*)QhG + bhoff + (size_t)rt * 16384;
    const char* ql_t = (const char*)QlG + bhoff + (size_t)rt * 16384;
    const char* kh_b = (const char*)KhG + bhoff;
    const char* kl_b = (const char*)KlG + bhoff;
    const char* vt_b = (const char*)VtG + bhoff;

    // stage Q hi/lo
    #pragma unroll
    for (int i = 0; i < 4; ++i) {
        int o = (w * 4 + i) * 1024;
        gl_lds(qh_t + o + lane * 16, (char*)KsH + o);
        gl_lds(ql_t + o + lane * 16, (char*)KsL + o);
    }
    __syncthreads();
    bf16x8 qfh[2][4], qfl[2][4];
    #pragma unroll
    for (int rf = 0; rf < 2; ++rf) {
        int rowA = 32 * wr + 16 * rf + ll;
        int sw = (rowA & 7) << 4;
        #pragma unroll
        for (int kk = 0; kk < 4; ++kk) {
            int off = (rowA * 256 + lg * 16 + kk * 64) ^ sw;
            qfh[rf][kk] = *(const bf16x8*)((const char*)KsH + off);
            qfl[rf][kk] = *(const bf16x8*)((const char*)KsL + off);
        }
    }
    float pm2[2][4];
    #pragma unroll
    for (int rf = 0; rf < 2; ++rf)
        #pragma unroll
        for (int r = 0; r < 4; ++r)
            pm2[rf][r] = pm_w[bh * S_LEN + row0 + 32 * wr + 16 * rf + 4 * lg + r] * LOG2E;
    __syncthreads();  // Q reads complete before tile-0 staging overwrites

    f32x4 zero4 = {0.f, 0.f, 0.f, 0.f};
    f32x4 accO[2][4];
    #pragma unroll
    for (int rf = 0; rf < 2; ++rf)
        #pragma unroll
        for (int vf = 0; vf < 4; ++vf) accO[rf][vf] = zero4;
    float rs[2][4] = {{0.f, 0.f, 0.f, 0.f}, {0.f, 0.f, 0.f, 0.f}};

    for (int ct = 0; ct <= rt; ++ct) {
        const char* kh_t = kh_b + (size_t)ct * 16384;
        const char* kl_t = kl_b + (size_t)ct * 16384;
        const char* vt_t = vt_b + (size_t)ct * 16384;
        #pragma unroll
        for (int i = 0; i < 4; ++i) {
            int o = (w * 4 + i) * 1024;
            gl_lds(kh_t + o + lane * 16, (char*)KsH + o);
            gl_lds(kl_t + o + lane * 16, (char*)KsL + o);
            gl_lds(vt_t + o + lane * 16, (char*)Vs + o);
        }
        if (t < 64) a_sh[t] = a_w[bh * S_LEN + ct * 64 + t] * LOG2E;
        __syncthreads();

        // QK^T: wave's 32x32 S-slice, split precision
        f32x4 accS[2][2];
        accS[0][0] = zero4; accS[0][1] = zero4; accS[1][0] = zero4; accS[1][1] = zero4;
        #pragma unroll
        for (int kk = 0; kk < 4; ++kk) {
            #pragma unroll
            for (int cf = 0; cf < 2; ++cf) {
                int rowB = 32 * wc + 16 * cf + ll;
                int off = (rowB * 256 + lg * 16 + kk * 64) ^ ((rowB & 7) << 4);
                bf16x8 kh = *(const bf16x8*)((const char*)KsH + off);
                bf16x8 klo = *(const bf16x8*)((const char*)KsL + off);
                #pragma unroll
                for (int rf = 0; rf < 2; ++rf) {
                    accS[rf][cf] = __builtin_amdgcn_mfma_f32_16x16x32_bf16(qfh[rf][kk], kh, accS[rf][cf], 0, 0, 0);
                    accS[rf][cf] = __builtin_amdgcn_mfma_f32_16x16x32_bf16(qfl[rf][kk], kh, accS[rf][cf], 0, 0, 0);
                    accS[rf][cf] = __builtin_amdgcn_mfma_f32_16x16x32_bf16(qfh[rf][kk], klo, accS[rf][cf], 0, 0, 0);
                }
            }
        }
        // decay epilogue -> Cs (bf16), rowsum
        const bool diag = (ct == rt);
        #pragma unroll
        for (int cf = 0; cf < 2; ++cf) {
            int jl = 32 * wc + 16 * cf + ll;
            float aj2 = a_sh[jl];
            #pragma unroll
            for (int rf = 0; rf < 2; ++rf) {
                #pragma unroll
                for (int r = 0; r < 4; ++r) {
                    int il = 32 * wr + 16 * rf + 4 * lg + r;
                    float cval = accS[rf][cf][r] * exp2f(aj2 - pm2[rf][r]);
                    if (diag && jl > il) cval = 0.f;
                    rs[rf][r] += cval;
                    *(ushort_t*)((char*)Cs + ((il * 128 + jl * 2) ^ ((il & 7) << 4))) = f2bf(cval);
                }
            }
        }
        __syncthreads();
        // PV: O rows 32*wr.., d-half 64*wc..
        #pragma unroll
        for (int kk = 0; kk < 2; ++kk) {
            #pragma unroll
            for (int rf = 0; rf < 2; ++rf) {
                int rowA = 32 * wr + 16 * rf + ll;
                int offA = (rowA * 128 + lg * 16 + kk * 64) ^ ((rowA & 7) << 4);
                bf16x8 afr = *(const bf16x8*)((const char*)Cs + offA);
                #pragma unroll
                for (int vf = 0; vf < 4; ++vf) {
                    int rowB = 64 * wc + 16 * vf + ll;
                    int offB = rowB * 128 + ((lg * 16 + kk * 64) ^ (((rowB & 7) ^ ((rowB >> 3) & 7)) << 4));
                    bf16x8 bfr = *(const bf16x8*)((const char*)Vs + offB);
                    accO[rf][vf] = __builtin_amdgcn_mfma_f32_16x16x32_bf16(afr, bfr, accO[rf][vf], 0, 0, 0);
                }
            }
        }
        __syncthreads();
    }

    // ---- finalize
    #pragma unroll
    for (int m = 1; m < 16; m <<= 1)
        #pragma unroll
        for (int rf = 0; rf < 2; ++rf)
            #pragma unroll
            for (int r = 0; r < 4; ++r) rs[rf][r] += __shfl_xor(rs[rf][r], m);
    if (ll == 0) {
        #pragma unroll
        for (int rf = 0; rf < 2; ++rf)
            #pragma unroll
            for (int r = 0; r < 4; ++r)
                red[wc][32 * wr + 16 * rf + 4 * lg + r] = rs[rf][r];
    }
    __syncthreads();
    float invn[2][4], scl[2][4];
    #pragma unroll
    for (int rf = 0; rf < 2; ++rf) {
        #pragma unroll
        for (int r = 0; r < 4; ++r) {
            int il = 32 * wr + 16 * rf + 4 * lg + r;
            float tot2 = red[0][il] + red[1][il];
            float pmn = pm_w[bh * S_LEN + row0 + il];
            float csn = cs_w[bh * S_LEN + row0 + il];
            float nm = fmaxf(fabsf(tot2), __expf(-(csn + pmn))) + 1e-6f;
            invn[rf][r] = 1.0f / nm;
        }
    }
    float ss[2][4] = {{0.f, 0.f, 0.f, 0.f}, {0.f, 0.f, 0.f, 0.f}};
    #pragma unroll
    for (int rf = 0; rf < 2; ++rf)
        #pragma unroll
        for (int vf = 0; vf < 4; ++vf)
            #pragma unroll
            for (int r = 0; r < 4; ++r) {
                float hv = accO[rf][vf][r] * invn[rf][r];
                ss[rf][r] += hv * hv;
            }
    #pragma unroll
    for (int m = 1; m < 16; m <<= 1)
        #pragma unroll
        for (int rf = 0; rf < 2; ++rf)
            #pragma unroll
            for (int r = 0; r < 4; ++r) ss[rf][r] += __shfl_xor(ss[rf][r], m);
    __syncthreads();
    if (ll == 0) {
        #pragma unroll
        for (int rf = 0; rf < 2; ++rf)
            #pragma unroll
            for (int r = 0; r < 4; ++r)
                red[wc][32 * wr + 16 * rf + 4 * lg + r] = ss[rf][r];
    }
    __syncthreads();
    #pragma unroll
    for (int rf = 0; rf < 2; ++rf)
        #pragma unroll
        for (int r = 0; r < 4; ++r) {
            int il = 32 * wr + 16 * rf + 4 * lg + r;
            float sst = red[0][il] + red[1][il];
            scl[rf][r] = rsqrtf(sst * (1.0f / 128.0f) + 1e-6f) * invn[rf][r];
        }
    float* ob = out + ((size_t)b * S_LEN + row0) * EMB_D + h * 128;
    #pragma unroll
    for (int rf = 0; rf < 2; ++rf)
        #pragma unroll
        for (int r = 0; r < 4; ++r) {
            int il = 32 * wr + 16 * rf + 4 * lg + r;
            #pragma unroll
            for (int vf = 0; vf < 4; ++vf) {
                int d = 64 * wc + 16 * vf + ll;
                ob[(size_t)il * EMB_D + d] = accO[rf][vf][r] * scl[rf][r];
            }
        }
}

extern "C" void kernel_launch(void* const* d_in, const int* in_sizes, int n_in,
                              void* d_out, int out_size, void* d_ws, size_t ws_size,
                              hipStream_t stream) {
    const float* q   = (const float*)d_in[0];
    const float* k   = (const float*)d_in[1];
    const float* v   = (const float*)d_in[2];
    const float* igk = (const float*)d_in[3];
    const float* igb = (const float*)d_in[4];
    const float* fgk = (const float*)d_in[5];
    const float* fgb = (const float*)d_in[6];
    float* out = (float*)d_out;

    char* W = (char*)d_ws;
    float* wt     = (float*)(W);
    float* igp_t  = (float*)(W + 196608);
    float* fgp_t  = (float*)(W + 327680);
    float* a_w    = (float*)(W + 458752);
    float* pm_w   = (float*)(W + 589824);
    float* cs_w   = (float*)(W + 720896);
    ushort_t* QhG = (ushort_t*)(W + 851968);
    ushort_t* QlG = (ushort_t*)(W + 851968 + 8388608ull);
    ushort_t* KhG = (ushort_t*)(W + 851968 + 2 * 8388608ull);
    ushort_t* KlG = (ushort_t*)(W + 851968 + 3 * 8388608ull);
    ushort_t* VtG = (ushort_t*)(W + 851968 + 4 * 8388608ull);

    ktrans<<<96, 256, 0, stream>>>(igk, fgk, wt);
    kgates<<<1024, 256, 0, stream>>>(q, k, v, igb, fgb, wt, igp_t, fgp_t, QhG, QlG, KhG, KlG);
    kvt<<<512, 256, 0, stream>>>(v, VtG);
    kscan<<<16, 64, 0, stream>>>(igp_t, fgp_t, a_w, pm_w, cs_w);
    kmain<<<512, 256, 0, stream>>>(QhG, QlG, KhG, KlG, VtG, a_w, pm_w, cs_w, out);
}

// Round 4
// 128.617 us; speedup vs baseline: 1.4176x; 1.4176x over previous
//
#include <hip/hip_runtime.h>

#define S_LEN 2048
#define EMB_D 1024
#define QK_SCALE 0.08838834764831845f  // 1/sqrt(128)
#define RS128 11.313708498984761f      // sqrt(128)
#define LOG2E 1.4426950408889634f

typedef __bf16 bf16x8 __attribute__((ext_vector_type(8)));
typedef float f32x4 __attribute__((ext_vector_type(4)));
typedef unsigned short ushort_t;

typedef const __attribute__((address_space(1))) void gvoid;
typedef __attribute__((address_space(3))) void lvoid;

__device__ __forceinline__ unsigned short f2bf(float x) {
    unsigned u = __float_as_uint(x);
    unsigned r = u + 0x7FFFu + ((u >> 16) & 1u);  // RNE
    return (unsigned short)(r >> 16);
}

__device__ __forceinline__ void bfsplit(float x, unsigned short& hi, unsigned short& lo) {
    hi = f2bf(x);
    lo = f2bf(x - __uint_as_float((unsigned)hi << 16));
}

__device__ __forceinline__ void gl_lds(const void* g, void* l) {
    __builtin_amdgcn_global_load_lds((gvoid*)g, (lvoid*)l, 16, 0, 0);
}

// ---------------- kernel 1: build W bf16 B-frag blobs. Wf[ks_g][lane][8elem],
// ks_g = src*32 + hemb*4 + ks. n = lane&15 (out col: 0-7 ig, 8-15 fg), lg = lane>>4.
// W row e = src*1024 + hemb*128 + ks*32 + lg*8 + e_i. q-rows scaled by sqrt(128).
__global__ __launch_bounds__(256) void ktransW(const float* __restrict__ igk,
                                               const float* __restrict__ fgk,
                                               ushort_t* __restrict__ Wf) {
    int gid = blockIdx.x * 256 + threadIdx.x;  // 0..6143
    int ks_g = gid >> 6, lane = gid & 63;
    int n = lane & 15, lg = lane >> 4;
    int src = ks_g >> 5, rem = ks_g & 31;
    int hemb = rem >> 2, ks = rem & 3;
    int e0 = src * 1024 + hemb * 128 + ks * 32 + lg * 8;
    float scale = (src == 0) ? RS128 : 1.0f;
    const float* col = (n < 8) ? igk : fgk;
    int nn = n & 7;
    union { ushort_t u[8]; uint4 v4; } P;
    #pragma unroll
    for (int e = 0; e < 8; ++e) P.u[e] = f2bf(col[(size_t)(e0 + e) * 8 + nn] * scale);
    *(uint4*)((char*)Wf + ks_g * 1024 + lane * 16) = P.v4;
}

// ---------------- kernel 2: streaming split. Per block = (bh, tile64).
// Writes LINEAR Qh/Ql/Kh/Kl bf16 tiles [64r][128d], and swizzled transposed Vt.
// No LDS, no barriers.
__global__ __launch_bounds__(256) void ksplit(const float* __restrict__ q,
                                              const float* __restrict__ k,
                                              const float* __restrict__ v,
                                              ushort_t* __restrict__ QhG,
                                              ushort_t* __restrict__ QlG,
                                              ushort_t* __restrict__ KhG,
                                              ushort_t* __restrict__ KlG,
                                              ushort_t* __restrict__ VtG) {
    const int blk = blockIdx.x;
    const int bh = blk >> 5, tile = blk & 31;
    const int b = bh >> 3, hh = bh & 7;
    const int t = threadIdx.x;
    const size_t rowbase = (size_t)b * S_LEN + tile * 64;
    const float* qb = q + rowbase * EMB_D + hh * 128;
    const float* kb = k + rowbase * EMB_D + hh * 128;
    const float* vb = v + rowbase * EMB_D + hh * 128;
    const size_t tb = ((size_t)bh * 32 + tile) * 16384;
    char* Qh = (char*)QhG + tb;
    char* Ql = (char*)QlG + tb;
    char* Kh = (char*)KhG + tb;
    char* Kl = (char*)KlG + tb;
    char* Vt = (char*)VtG + tb;

    #pragma unroll
    for (int i = 0; i < 8; ++i) {
        int f = i * 256 + t;           // float4 idx 0..2047
        int r = f >> 5, c4 = f & 31;
        int off = r * 256 + c4 * 8;
        float4 fq = *(const float4*)(qb + (size_t)r * EMB_D + c4 * 4);
        ushort4 H, L;
        bfsplit(fq.x * QK_SCALE, H.x, L.x);
        bfsplit(fq.y * QK_SCALE, H.y, L.y);
        bfsplit(fq.z * QK_SCALE, H.z, L.z);
        bfsplit(fq.w * QK_SCALE, H.w, L.w);
        *(ushort4*)(Qh + off) = H;
        *(ushort4*)(Ql + off) = L;
        float4 fk = *(const float4*)(kb + (size_t)r * EMB_D + c4 * 4);
        bfsplit(fk.x, H.x, L.x);
        bfsplit(fk.y, H.y, L.y);
        bfsplit(fk.z, H.z, L.z);
        bfsplit(fk.w, H.w, L.w);
        *(ushort4*)(Kh + off) = H;
        *(ushort4*)(Kl + off) = L;
    }
    // V transpose: thread owns column d, 32 rows in registers. Coalesced row loads.
    const int d = t & 127, half2 = t >> 7;
    const int jb = half2 * 32;
    float col[32];
    #pragma unroll
    for (int j = 0; j < 32; ++j)
        col[j] = vb[(size_t)(jb + j) * EMB_D + d];
    const int swz = ((d & 7) ^ ((d >> 3) & 7)) << 4;
    #pragma unroll
    for (int g = 0; g < 4; ++g) {
        union { ushort_t u[8]; uint4 v4; } P;
        #pragma unroll
        for (int e = 0; e < 8; ++e) P.u[e] = f2bf(col[g * 8 + e]);
        *(uint4*)(Vt + ((d * 128 + (jb + g * 8) * 2) ^ swz)) = P.v4;
    }
}

// ---------------- kernel 3: gate GEMM via MFMA. 128 blocks = (b, tile, half32).
// Wave w: M-strip m = w>>1 (16 rows), K-half kh = w&1 (12 of 24 (src,hemb) rounds).
// x A-frags from per-wave LDS (source-XOR swizzled staging); W B-frags from global.
__global__ __launch_bounds__(256) void kgemm(const ushort_t* __restrict__ QhG,
                                             const ushort_t* __restrict__ KhG,
                                             const float* __restrict__ v,
                                             const ushort_t* __restrict__ Wf,
                                             const float* __restrict__ igb,
                                             const float* __restrict__ fgb,
                                             float* __restrict__ igp_t,
                                             float* __restrict__ fgp_t) {
    __shared__ __align__(16) ushort_t xs[4][2048];   // 4 KB per wave
    __shared__ __align__(16) float red[4][64][4];
    const int blk = blockIdx.x;
    const int b = blk >> 6, tile = (blk >> 1) & 31, half = blk & 1;
    const int t = threadIdx.x, w = t >> 6, lane = t & 63;
    const int m = w >> 1, kh = w & 1;
    const int ll = lane & 15, lg = lane >> 4;
    const int lrow = half * 32 + m * 16;   // tile-local strip row
    const int s0 = tile * 64 + lrow;       // seq row of strip
    f32x4 acc = {0.f, 0.f, 0.f, 0.f};
    char* myx = (char*)xs + w * 4096;

    for (int ri = kh * 12; ri < kh * 12 + 12; ++ri) {
        int src = ri >> 3, hemb = ri & 7;
        if (src < 2) {
            const char* tp = (const char*)(src ? KhG : QhG)
                           + ((size_t)(b * 8 + hemb) * 32 + tile) * 16384 + lrow * 256;
            #pragma unroll
            for (int i = 0; i < 4; ++i) {
                int a = i * 1024 + lane * 16;
                int sidx = a ^ (((a >> 8) & 7) << 4);
                gl_lds(tp + sidx, myx + i * 1024);
            }
            asm volatile("s_waitcnt vmcnt(0)" ::: "memory");
        } else {
            const float* vb = v + ((size_t)b * S_LEN + s0) * EMB_D + hemb * 128;
            #pragma unroll
            for (int i = 0; i < 8; ++i) {
                int f = i * 64 + lane;     // 512 float4 = 16 rows x 32
                int r = f >> 5, c4 = f & 31;
                float4 g = *(const float4*)(vb + (size_t)r * EMB_D + c4 * 4);
                ushort4 H;
                H.x = f2bf(g.x); H.y = f2bf(g.y); H.z = f2bf(g.z); H.w = f2bf(g.w);
                int off = (r * 256 + c4 * 8) ^ ((r & 7) << 4);
                *(ushort4*)(myx + off) = H;
            }
        }
        bf16x8 bf[4];
        #pragma unroll
        for (int ks = 0; ks < 4; ++ks)
            bf[ks] = *(const bf16x8*)((const char*)Wf + (src * 32 + hemb * 4 + ks) * 1024 + lane * 16);
        #pragma unroll
        for (int ks = 0; ks < 4; ++ks) {
            int aoff = (ll * 256 + lg * 16 + ks * 64) ^ ((ll & 7) << 4);
            bf16x8 af = *(const bf16x8*)(myx + aoff);
            acc = __builtin_amdgcn_mfma_f32_16x16x32_bf16(af, bf[ks], acc, 0, 0, 0);
        }
    }
    *(f32x4*)&red[w][lane][0] = acc;
    __syncthreads();
    if (kh == 0) {
        f32x4 o2 = acc + *(const f32x4*)&red[w + 1][lane][0];
        float bias = (ll < 8) ? igb[ll] : fgb[ll - 8];
        float* dst = (ll < 8) ? igp_t : fgp_t;
        size_t ob = (size_t)(b * 8 + (ll & 7)) * S_LEN + s0 + lg * 4;
        #pragma unroll
        for (int reg = 0; reg < 4; ++reg) dst[ob + reg] = o2[reg] + bias;
    }
}

// ---------------- kernel 4: per-(b,h) prefix scans, single wave, no barriers.
__global__ __launch_bounds__(64) void kscan(const float* __restrict__ igp_t,
                                            const float* __restrict__ fgp_t,
                                            float* __restrict__ a_w,
                                            float* __restrict__ pm_w,
                                            float* __restrict__ cs_w) {
    const int bh = blockIdx.x;
    const int l = threadIdx.x;
    const int base = bh * S_LEN + l * 32;
    float lf[32];
    #pragma unroll
    for (int i = 0; i < 8; ++i) {
        float4 fg = *(const float4*)(fgp_t + base + i * 4);
        float* p = &lf[i * 4];
        p[0] = fminf(fg.x, 0.f) - log1pf(__expf(-fabsf(fg.x)));
        p[1] = fminf(fg.y, 0.f) - log1pf(__expf(-fabsf(fg.y)));
        p[2] = fminf(fg.z, 0.f) - log1pf(__expf(-fabsf(fg.z)));
        p[3] = fminf(fg.w, 0.f) - log1pf(__expf(-fabsf(fg.w)));
    }
    #pragma unroll
    for (int i = 1; i < 32; ++i) lf[i] += lf[i - 1];
    float tot = lf[31];
    #pragma unroll
    for (int d = 1; d < 64; d <<= 1) {
        float n = __shfl_up(tot, d, 64);
        if (l >= d) tot += n;
    }
    float excl = tot - lf[31];
    float a[32];
    #pragma unroll
    for (int i = 0; i < 8; ++i) {
        float4 ig = *(const float4*)(igp_t + base + i * 4);
        float iv[4] = {ig.x, ig.y, ig.z, ig.w};
        #pragma unroll
        for (int e = 0; e < 4; ++e) {
            int idx = i * 4 + e;
            float cs = excl + lf[idx];
            cs_w[base + idx] = cs;
            a[idx] = iv[e] - cs;
            a_w[base + idx] = a[idx];
        }
    }
    float am[32];
    am[0] = a[0];
    #pragma unroll
    for (int i = 1; i < 32; ++i) am[i] = fmaxf(am[i - 1], a[i]);
    float mtot = am[31];
    #pragma unroll
    for (int d = 1; d < 64; d <<= 1) {
        float n = __shfl_up(mtot, d, 64);
        if (l >= d) mtot = fmaxf(mtot, n);
    }
    float exm = __shfl_up(mtot, 1, 64);
    if (l == 0) exm = -INFINITY;
    #pragma unroll
    for (int i = 0; i < 32; ++i) pm_w[base + i] = fmaxf(exm, am[i]);
}

// ---------------- kernel 5: main core. 512 blocks x 256 thr (4 waves, 2x2 grid).
// Staging via global_load_lds from LINEAR Q/K tiles with inverse-swizzled source
// addresses (LDS ends up swizzled); Vt pre-swizzled. QK^T split precision.
__global__ __launch_bounds__(256) void kmain(const ushort_t* __restrict__ QhG,
                                             const ushort_t* __restrict__ QlG,
                                             const ushort_t* __restrict__ KhG,
                                             const ushort_t* __restrict__ KlG,
                                             const ushort_t* __restrict__ VtG,
                                             const float* __restrict__ a_w,
                                             const float* __restrict__ pm_w,
                                             const float* __restrict__ cs_w,
                                             float* __restrict__ out) {
    __shared__ __align__(16) ushort_t KsH[8192];
    __shared__ __align__(16) ushort_t KsL[8192];
    __shared__ __align__(16) ushort_t Vs[8192];
    __shared__ __align__(16) ushort_t Cs[4096];
    __shared__ float a_sh[64];
    __shared__ float red[2][64];

    const int blk = blockIdx.x;
    const int bh = blk & 15;              // bh&7 == XCD -> per-bh L2 affinity
    const int rt = 31 - (blk >> 4);       // longest-first
    const int row0 = rt * 64;
    const int b = bh >> 3, h = bh & 7;
    const int t = threadIdx.x;
    const int w = t >> 6, lane = t & 63;
    const int wr = w >> 1, wc = w & 1;
    const int lg = lane >> 4, ll = lane & 15;

    const size_t bhoff = (size_t)bh * 524288;
    const char* qh_t = (const char*)QhG + bhoff + (size_t)rt * 16384;
    const char* ql_t = (const char*)QlG + bhoff + (size_t)rt * 16384;
    const char* kh_b = (const char*)KhG + bhoff;
    const char* kl_b = (const char*)KlG + bhoff;
    const char* vt_b = (const char*)VtG + bhoff;

    // stage Q hi/lo (source-XOR)
    #pragma unroll
    for (int i = 0; i < 4; ++i) {
        int o = (w * 4 + i) * 1024;
        int a = o + lane * 16;
        int sidx = a ^ (((a >> 8) & 7) << 4);
        gl_lds(qh_t + sidx, (char*)KsH + o);
        gl_lds(ql_t + sidx, (char*)KsL + o);
    }
    __syncthreads();
    bf16x8 qfh[2][4], qfl[2][4];
    #pragma unroll
    for (int rf = 0; rf < 2; ++rf) {
        int rowA = 32 * wr + 16 * rf + ll;
        int sw = (rowA & 7) << 4;
        #pragma unroll
        for (int kk = 0; kk < 4; ++kk) {
            int off = (rowA * 256 + lg * 16 + kk * 64) ^ sw;
            qfh[rf][kk] = *(const bf16x8*)((const char*)KsH + off);
            qfl[rf][kk] = *(const bf16x8*)((const char*)KsL + off);
        }
    }
    float pm2[2][4];
    #pragma unroll
    for (int rf = 0; rf < 2; ++rf)
        #pragma unroll
        for (int r = 0; r < 4; ++r)
            pm2[rf][r] = pm_w[bh * S_LEN + row0 + 32 * wr + 16 * rf + 4 * lg + r] * LOG2E;
    __syncthreads();

    f32x4 zero4 = {0.f, 0.f, 0.f, 0.f};
    f32x4 accO[2][4];
    #pragma unroll
    for (int rf = 0; rf < 2; ++rf)
        #pragma unroll
        for (int vf = 0; vf < 4; ++vf) accO[rf][vf] = zero4;
    float rs[2][4] = {{0.f, 0.f, 0.f, 0.f}, {0.f, 0.f, 0.f, 0.f}};

    for (int ct = 0; ct <= rt; ++ct) {
        const char* kh_t = kh_b + (size_t)ct * 16384;
        const char* kl_t = kl_b + (size_t)ct * 16384;
        const char* vt_t = vt_b + (size_t)ct * 16384;
        #pragma unroll
        for (int i = 0; i < 4; ++i) {
            int o = (w * 4 + i) * 1024;
            int a = o + lane * 16;
            int sidx = a ^ (((a >> 8) & 7) << 4);
            gl_lds(kh_t + sidx, (char*)KsH + o);
            gl_lds(kl_t + sidx, (char*)KsL + o);
            gl_lds(vt_t + a, (char*)Vs + o);
        }
        if (t < 64) a_sh[t] = a_w[bh * S_LEN + ct * 64 + t] * LOG2E;
        __syncthreads();

        f32x4 accS[2][2];
        accS[0][0] = zero4; accS[0][1] = zero4; accS[1][0] = zero4; accS[1][1] = zero4;
        #pragma unroll
        for (int kk = 0; kk < 4; ++kk) {
            #pragma unroll
            for (int cf = 0; cf < 2; ++cf) {
                int rowB = 32 * wc + 16 * cf + ll;
                int off = (rowB * 256 + lg * 16 + kk * 64) ^ ((rowB & 7) << 4);
                bf16x8 kh = *(const bf16x8*)((const char*)KsH + off);
                bf16x8 klo = *(const bf16x8*)((const char*)KsL + off);
                #pragma unroll
                for (int rf = 0; rf < 2; ++rf) {
                    accS[rf][cf] = __builtin_amdgcn_mfma_f32_16x16x32_bf16(qfh[rf][kk], kh, accS[rf][cf], 0, 0, 0);
                    accS[rf][cf] = __builtin_amdgcn_mfma_f32_16x16x32_bf16(qfl[rf][kk], kh, accS[rf][cf], 0, 0, 0);
                    accS[rf][cf] = __builtin_amdgcn_mfma_f32_16x16x32_bf16(qfh[rf][kk], klo, accS[rf][cf], 0, 0, 0);
                }
            }
        }
        const bool diag = (ct == rt);
        #pragma unroll
        for (int cf = 0; cf < 2; ++cf) {
            int jl = 32 * wc + 16 * cf + ll;
            float aj2 = a_sh[jl];
            #pragma unroll
            for (int rf = 0; rf < 2; ++rf) {
                #pragma unroll
                for (int r = 0; r < 4; ++r) {
                    int il = 32 * wr + 16 * rf + 4 * lg + r;
                    float cval = accS[rf][cf][r] * exp2f(aj2 - pm2[rf][r]);
                    if (diag && jl > il) cval = 0.f;
                    rs[rf][r] += cval;
                    *(ushort_t*)((char*)Cs + ((il * 128 + jl * 2) ^ ((il & 7) << 4))) = f2bf(cval);
                }
            }
        }
        __syncthreads();
        #pragma unroll
        for (int kk = 0; kk < 2; ++kk) {
            #pragma unroll
            for (int rf = 0; rf < 2; ++rf) {
                int rowA = 32 * wr + 16 * rf + ll;
                int offA = (rowA * 128 + lg * 16 + kk * 64) ^ ((rowA & 7) << 4);
                bf16x8 afr = *(const bf16x8*)((const char*)Cs + offA);
                #pragma unroll
                for (int vf = 0; vf < 4; ++vf) {
                    int rowB = 64 * wc + 16 * vf + ll;
                    int offB = rowB * 128 + ((lg * 16 + kk * 64) ^ (((rowB & 7) ^ ((rowB >> 3) & 7)) << 4));
                    bf16x8 bfr = *(const bf16x8*)((const char*)Vs + offB);
                    accO[rf][vf] = __builtin_amdgcn_mfma_f32_16x16x32_bf16(afr, bfr, accO[rf][vf], 0, 0, 0);
                }
            }
        }
        __syncthreads();
    }

    // ---- finalize
    #pragma unroll
    for (int m = 1; m < 16; m <<= 1)
        #pragma unroll
        for (int rf = 0; rf < 2; ++rf)
            #pragma unroll
            for (int r = 0; r < 4; ++r) rs[rf][r] += __shfl_xor(rs[rf][r], m);
    if (ll == 0) {
        #pragma unroll
        for (int rf = 0; rf < 2; ++rf)
            #pragma unroll
            for (int r = 0; r < 4; ++r)
                red[wc][32 * wr + 16 * rf + 4 * lg + r] = rs[rf][r];
    }
    __syncthreads();
    float invn[2][4], scl[2][4];
    #pragma unroll
    for (int rf = 0; rf < 2; ++rf) {
        #pragma unroll
        for (int r = 0; r < 4; ++r) {
            int il = 32 * wr + 16 * rf + 4 * lg + r;
            float tot2 = red[0][il] + red[1][il];
            float pmn = pm_w[bh * S_LEN + row0 + il];
            float csn = cs_w[bh * S_LEN + row0 + il];
            float nm = fmaxf(fabsf(tot2), __expf(-(csn + pmn))) + 1e-6f;
            invn[rf][r] = 1.0f / nm;
        }
    }
    float ss[2][4] = {{0.f, 0.f, 0.f, 0.f}, {0.f, 0.f, 0.f, 0.f}};
    #pragma unroll
    for (int rf = 0; rf < 2; ++rf)
        #pragma unroll
        for (int vf = 0; vf < 4; ++vf)
            #pragma unroll
            for (int r = 0; r < 4; ++r) {
                float hv = accO[rf][vf][r] * invn[rf][r];
                ss[rf][r] += hv * hv;
            }
    #pragma unroll
    for (int m = 1; m < 16; m <<= 1)
        #pragma unroll
        for (int rf = 0; rf < 2; ++rf)
            #pragma unroll
            for (int r = 0; r < 4; ++r) ss[rf][r] += __shfl_xor(ss[rf][r], m);
    __syncthreads();
    if (ll == 0) {
        #pragma unroll
        for (int rf = 0; rf < 2; ++rf)
            #pragma unroll
            for (int r = 0; r < 4; ++r)
                red[wc][32 * wr + 16 * rf + 4 * lg + r] = ss[rf][r];
    }
    __syncthreads();
    #pragma unroll
    for (int rf = 0; rf < 2; ++rf)
        #pragma unroll
        for (int r = 0; r < 4; ++r) {
            int il = 32 * wr + 16 * rf + 4 * lg + r;
            float sst = red[0][il] + red[1][il];
            scl[rf][r] = rsqrtf(sst * (1.0f / 128.0f) + 1e-6f) * invn[rf][r];
        }
    float* ob = out + ((size_t)b * S_LEN + row0) * EMB_D + h * 128;
    #pragma unroll
    for (int rf = 0; rf < 2; ++rf)
        #pragma unroll
        for (int r = 0; r < 4; ++r) {
            int il = 32 * wr + 16 * rf + 4 * lg + r;
            #pragma unroll
            for (int vf = 0; vf < 4; ++vf) {
                int d = 64 * wc + 16 * vf + ll;
                ob[(size_t)il * EMB_D + d] = accO[rf][vf][r] * scl[rf][r];
            }
        }
}

extern "C" void kernel_launch(void* const* d_in, const int* in_sizes, int n_in,
                              void* d_out, int out_size, void* d_ws, size_t ws_size,
                              hipStream_t stream) {
    const float* q   = (const float*)d_in[0];
    const float* k   = (const float*)d_in[1];
    const float* v   = (const float*)d_in[2];
    const float* igk = (const float*)d_in[3];
    const float* igb = (const float*)d_in[4];
    const float* fgk = (const float*)d_in[5];
    const float* fgb = (const float*)d_in[6];
    float* out = (float*)d_out;

    char* W = (char*)d_ws;
    ushort_t* Wf   = (ushort_t*)(W);                 //  98304 B
    float* igp_t   = (float*)(W + 98304);            // 131072 B
    float* fgp_t   = (float*)(W + 229376);
    float* a_w     = (float*)(W + 360448);
    float* pm_w    = (float*)(W + 491520);
    float* cs_w    = (float*)(W + 622592);
    ushort_t* QhG  = (ushort_t*)(W + 753664);        // 8 MB each
    ushort_t* QlG  = (ushort_t*)(W + 753664 + 1 * 8388608ull);
    ushort_t* KhG  = (ushort_t*)(W + 753664 + 2 * 8388608ull);
    ushort_t* KlG  = (ushort_t*)(W + 753664 + 3 * 8388608ull);
    ushort_t* VtG  = (ushort_t*)(W + 753664 + 4 * 8388608ull);  // total ~42.7 MB

    ktransW<<<24, 256, 0, stream>>>(igk, fgk, Wf);
    ksplit<<<512, 256, 0, stream>>>(q, k, v, QhG, QlG, KhG, KlG, VtG);
    kgemm<<<128, 256, 0, stream>>>(QhG, KhG, v, Wf, igb, fgb, igp_t, fgp_t);
    kscan<<<16, 64, 0, stream>>>(igp_t, fgp_t, a_w, pm_w, cs_w);
    kmain<<<512, 256, 0, stream>>>(QhG, QlG, KhG, KlG, VtG, a_w, pm_w, cs_w, out);
}